// Round 16
// baseline (499.592 us; speedup 1.0000x reference)
//
#include <hip/hip_runtime.h>

#define HW 512
#define NSTATE (HW * HW)   // 262144
#define NC4_X 196608       // x as float4 (3*H*W/4)
#define NC4_POLROW 262144  // Wpol row stride in float4 (4 MiB)
#define NC4_V 65536        // v as float4

#define CH4 1024   // float4 per wave-chunk (16 KB)
#define NCH_X 192  // chunks per W1 row
#define SPAN_ROP 1024

// ws layout (float offsets)
#define WS_PART1 0      // 192*32 = 6144
#define WS_PARTP 6144   // 256*32 = 8192
#define WS_H2 14336     // 64
#define WS_P 14400      // 262144
#define WS_RD (WS_P + NSTATE)
#define WS_V (WS_RD + NSTATE)
// probe discard regions (32 MB into ~512 MB ws)
#define WS_DISC 8388608
#define WS_DISC_POL (WS_DISC)                  // 5*8192
#define WS_DISC_ROP_P (WS_DISC + 65536)        // 262144
#define WS_DISC_ROP_RD (WS_DISC + 327680)      // 262144
#define WS_DISC_VAL (WS_DISC + 1048576)        // 262144

#define SGB __builtin_amdgcn_sched_group_barrier

__device__ __forceinline__ float wred(float a) {
  a += __shfl_xor(a, 32);
  a += __shfl_xor(a, 16);
  a += __shfl_xor(a, 8);
  a += __shfl_xor(a, 4);
  a += __shfl_xor(a, 2);
  a += __shfl_xor(a, 1);
  return a;
}

__device__ __forceinline__ float span_dot(const float4* __restrict__ wp,
                                          const float4* __restrict__ xp) {
  float acc = 0.f;
#pragma unroll
  for (int bt = 0; bt < 2; ++bt) {
    float4 w[8], xv[8];
#pragma unroll
    for (int j = 0; j < 8; ++j) w[j] = wp[bt * 512 + j * 64];
#pragma unroll
    for (int j = 0; j < 8; ++j) xv[j] = xp[bt * 512 + j * 64];
    SGB(0x020, 16, 0);
#pragma unroll
    for (int j = 0; j < 8; ++j)
      acc += w[j].x * xv[j].x + w[j].y * xv[j].y + w[j].z * xv[j].z +
             w[j].w * xv[j].w;
  }
  return acc;
}

// ---------------------------------------------------------------------------
// K1: W1@x partials, flat-linear (budget ~15 µs, triangulated via R10).
// ---------------------------------------------------------------------------
__global__ __launch_bounds__(256) void mv_w1(const float4* __restrict__ W1,
                                             const float4* __restrict__ x,
                                             float* __restrict__ part1) {
  int b = blockIdx.x;  // [0,1536)
  int row = b / 48, cb = b - row * 48;
  int tid = threadIdx.x, wave = tid >> 6, lane = tid & 63;
  int ch = cb * 4 + wave;
  const float4* __restrict__ wp =
      W1 + (size_t)row * NC4_X + (size_t)ch * CH4 + lane;
  const float4* __restrict__ xp = x + (size_t)ch * CH4 + lane;
  float acc = span_dot(wp, xp);
  acc = wred(acc);
  if (lane == 0) part1[ch * 32 + row] = acc;
}

// ---------------------------------------------------------------------------
// finish_h
// ---------------------------------------------------------------------------
__global__ __launch_bounds__(1024) void finish_h(
    const float* __restrict__ partials, const float* __restrict__ b1,
    const float* __restrict__ W2, const float* __restrict__ b2,
    float* __restrict__ h2out) {
  __shared__ float red[32][32];
  __shared__ float h1[32];
  int tid = threadIdx.x;
  int row = tid & 31, grp = tid >> 5;
  float s = 0.f;
  for (int b = grp; b < NCH_X; b += 32) s += partials[b * 32 + row];
  red[grp][row] = s;
  __syncthreads();
  if (tid < 32) {
    float t = b1[tid];
    for (int g = 0; g < 32; ++g) t += red[g][tid];
    h1[tid] = fmaxf(t, 0.f);
  }
  __syncthreads();
  if (tid < 64) {
    float t = b2[tid];
    for (int k = 0; k < 32; ++k) t += W2[tid * 32 + k] * h1[k];
    h2out[tid] = fmaxf(t, 0.f);
  }
}

// ---------------------------------------------------------------------------
// K3 PROBE: rop x3 — rep 0 real, reps 1-2 write identical values to discard.
// Measures rop's true duration + counters directly (never measured since R5).
// ---------------------------------------------------------------------------
__global__ __launch_bounds__(256) void rop_kernel(
    const float4* __restrict__ Wro4, const float* __restrict__ bro,
    const float4* __restrict__ Wri4, const float* __restrict__ bri,
    const float4* __restrict__ Wp4, const float* __restrict__ bp,
    const float* __restrict__ h2, float* __restrict__ p_out,
    float* __restrict__ rd_out, float* __restrict__ disc_p,
    float* __restrict__ disc_rd) {
  __shared__ float dots[4][3][64];
  int rep = blockIdx.x >> 10;   // 0..2
  int blk = blockIdx.x & 1023;  // [0,1024)
  int tid = threadIdx.x;
  int wave = tid >> 6, lane = tid & 63;
  int grp = lane >> 4;
  float4 h4 = ((const float4*)h2)[lane & 15];
  int span = blk * 4 + wave;
  size_t base = (size_t)span * SPAN_ROP;
  const float4* mats[3] = {Wro4, Wri4, Wp4};
#pragma unroll
  for (int m = 0; m < 3; ++m) {
    const float4* __restrict__ W = mats[m] + base + lane;
#pragma unroll
    for (int batch = 0; batch < 2; ++batch) {
      float4 w[8];
#pragma unroll
      for (int j = 0; j < 8; ++j) w[j] = W[(batch * 8 + j) * 64];
      SGB(0x020, 8, 0);
      float part[8];
#pragma unroll
      for (int j = 0; j < 8; ++j)
        part[j] = w[j].x * h4.x + w[j].y * h4.y + w[j].z * h4.z + w[j].w * h4.w;
#pragma unroll
      for (int j = 0; j < 8; ++j) {
        part[j] += __shfl_xor(part[j], 8);
        part[j] += __shfl_xor(part[j], 4);
        part[j] += __shfl_xor(part[j], 2);
        part[j] += __shfl_xor(part[j], 1);
      }
      if ((lane & 15) == 0) {
#pragma unroll
        for (int j = 0; j < 8; ++j)
          dots[wave][m][(batch * 8 + j) * 4 + grp] = part[j];
      }
    }
  }
  __syncthreads();
  int o = blk * 256 + tid;
  float dro = dots[tid >> 6][0][tid & 63] + bro[o];
  float dri = dots[tid >> 6][1][tid & 63] + bri[o];
  float dp = dots[tid >> 6][2][tid & 63] + bp[o];
  float sro = 1.f / (1.f + __expf(-dro));
  float sri = 1.f / (1.f + __expf(-dri));
  float pv = 1.f / (1.f + __expf(-dp));
  float* po = rep ? disc_p : p_out;
  float* ro = rep ? disc_rd : rd_out;
  po[o] = pv;
  ro[o] = sri - sro;
}

// ---------------------------------------------------------------------------
// K4 PROBE: valiter x16 — rep 0 real, reps 1-15 write identical values to
// discard. Measures valiter's true duration + counters directly.
// ---------------------------------------------------------------------------
#define TILE 16
#define HALO 10
#define LR 36
__global__ __launch_bounds__(256) void valiter_kernel(
    const float* __restrict__ p, const float* __restrict__ rd,
    float* __restrict__ vout, float* __restrict__ disc) {
  __shared__ float u[LR + 2][LR + 3];
  __shared__ float pp[LR][LR + 1];
  __shared__ float rr[LR][LR + 1];
  __shared__ float vv[LR][LR + 1];
  int rep = blockIdx.x >> 10;   // 0..15
  int blk = blockIdx.x & 1023;  // [0,1024)
  int tid = threadIdx.x;
  int ti = blk >> 5, tj = blk & 31;
  int gi0 = ti * TILE - HALO, gj0 = tj * TILE - HALO;
  for (int idx = tid; idx < (LR + 2) * (LR + 3); idx += 256)
    ((float*)u)[idx] = 0.f;
  for (int idx = tid; idx < LR * LR; idx += 256) {
    int i = idx / LR, j = idx % LR;
    int gi = gi0 + i, gj = gj0 + j;
    bool ok = (gi >= 0) & (gi < HW) & (gj >= 0) & (gj < HW);
    pp[i][j] = ok ? p[gi * HW + gj] : 0.f;
    rr[i][j] = ok ? rd[gi * HW + gj] : 0.f;
    vv[i][j] = 0.f;
  }
  __syncthreads();
  for (int k = 0; k < 10; ++k) {
#pragma unroll
    for (int idx = tid; idx < LR * LR; idx += 256) {
      int i = idx / LR, j = idx % LR;
      u[i + 1][j + 1] = vv[i][j] * pp[i][j] + rr[i][j];
    }
    __syncthreads();
#pragma unroll
    for (int idx = tid; idx < LR * LR; idx += 256) {
      int i = idx / LR, j = idx % LR;
      float m = u[i][j];
      m = fmaxf(m, u[i][j + 1]);
      m = fmaxf(m, u[i][j + 2]);
      m = fmaxf(m, u[i + 1][j]);
      m = fmaxf(m, u[i + 1][j + 2]);
      m = fmaxf(m, u[i + 2][j]);
      m = fmaxf(m, u[i + 2][j + 1]);
      m = fmaxf(m, u[i + 2][j + 2]);
      vv[i][j] = m;
    }
    __syncthreads();
  }
  if (tid < TILE * TILE) {
    int a = tid >> 4, b = tid & 15;
    float val = vv[HALO + a][HALO + b];
    if (rep == 0)
      vout[(ti * TILE + a) * HW + tj * TILE + b] = val;
    else
      disc[blk * 256 + tid] = val;  // identical across reps: deterministic
  }
}

// ---------------------------------------------------------------------------
// K5 PROBE: mv_pol x5 — rep 0 real, reps 1-4 discard. Separates cold unit
// time (dispatch - 4x17 µs warm) now that it's forced into top-5.
// ---------------------------------------------------------------------------
__global__ __launch_bounds__(256) void mv_pol(const float4* __restrict__ Wpol,
                                              const float4* __restrict__ x,
                                              const float4* __restrict__ v,
                                              float* __restrict__ partP,
                                              float* __restrict__ disc) {
  int rep = blockIdx.x >> 11;  // 0..4
  int b = blockIdx.x & 2047;   // [0,2048)
  int tid = threadIdx.x, wave = tid >> 6, lane = tid & 63;
  int f = b * 4 + wave;
  int row = f >> 8, rc = f & 255;
  const float4* __restrict__ wp = Wpol + (size_t)f * CH4 + lane;
  const float4* __restrict__ xp =
      (rc < 64) ? (v + (size_t)rc * CH4 + lane)
                : (x + (size_t)(rc - 64) * CH4 + lane);
  float acc = span_dot(wp, xp);
  acc = wred(acc);
  float* outp = (rep == 0) ? partP : (disc + rep * 8192);
  if (lane == 0) outp[rc * 32 + row] = acc;
}

// ---------------------------------------------------------------------------
// finish_pol
// ---------------------------------------------------------------------------
__global__ __launch_bounds__(1024) void finish_pol(
    const float* __restrict__ partP, const float* __restrict__ bpol,
    const float* __restrict__ Whead, const float* __restrict__ bhead,
    const float* __restrict__ v, const int* __restrict__ pos,
    float* __restrict__ out) {
  __shared__ float red[32][32];
  __shared__ float hp[32];
  __shared__ float logits[8];
  int tid = threadIdx.x;
  int row = tid & 31, grp = tid >> 5;
  float s = 0.f;
  for (int b = grp; b < 256; b += 32) s += partP[b * 32 + row];
  red[grp][row] = s;
  __syncthreads();
  if (tid < 32) {
    float t = bpol[tid];
    for (int g = 0; g < 32; ++g) t += red[g][tid];
    hp[tid] = fmaxf(t, 0.f);
  }
  __syncthreads();
  if (tid < 8) {
    float t = bhead[tid];
    for (int k = 0; k < 32; ++k) t += Whead[tid * 32 + k] * hp[k];
    logits[tid] = t;
  }
  __syncthreads();
  if (tid == 0) {
    float mx = logits[0];
    for (int j = 1; j < 8; ++j) mx = fmaxf(mx, logits[j]);
    float e[8], sum = 0.f;
    for (int j = 0; j < 8; ++j) {
      e[j] = __expf(logits[j] - mx);
      sum += e[j];
    }
    for (int j = 0; j < 8; ++j) out[j] = e[j] / sum;
    out[8] = v[pos[0] * HW + pos[1]];
  }
}

extern "C" void kernel_launch(void* const* d_in, const int* in_sizes, int n_in,
                              void* d_out, int out_size, void* d_ws,
                              size_t ws_size, hipStream_t stream) {
  const float* x = (const float*)d_in[0];
  const int* pos = (const int*)d_in[1];
  const float* W1 = (const float*)d_in[2];
  const float* b1 = (const float*)d_in[3];
  const float* W2 = (const float*)d_in[4];
  const float* b2 = (const float*)d_in[5];
  const float* Wro = (const float*)d_in[6];
  const float* bro = (const float*)d_in[7];
  const float* Wri = (const float*)d_in[8];
  const float* bri = (const float*)d_in[9];
  const float* Wp = (const float*)d_in[10];
  const float* bp = (const float*)d_in[11];
  const float* Wpol = (const float*)d_in[12];
  const float* bpol = (const float*)d_in[13];
  const float* Whead = (const float*)d_in[14];
  const float* bhead = (const float*)d_in[15];
  float* ws = (float*)d_ws;
  float* out = (float*)d_out;

  float* part1 = ws + WS_PART1;
  float* partP = ws + WS_PARTP;
  float* h2 = ws + WS_H2;
  float* pbuf = ws + WS_P;
  float* rdbuf = ws + WS_RD;
  float* vbuf = ws + WS_V;

  mv_w1<<<1536, 256, 0, stream>>>((const float4*)W1, (const float4*)x, part1);
  finish_h<<<1, 1024, 0, stream>>>(part1, b1, W2, b2, h2);
  // PROBE: rop x3
  rop_kernel<<<3072, 256, 0, stream>>>(
      (const float4*)Wro, bro, (const float4*)Wri, bri, (const float4*)Wp, bp,
      h2, pbuf, rdbuf, ws + WS_DISC_ROP_P, ws + WS_DISC_ROP_RD);
  // PROBE: valiter x16
  valiter_kernel<<<16384, 256, 0, stream>>>(pbuf, rdbuf, vbuf,
                                            ws + WS_DISC_VAL);
  // PROBE: mv_pol x5
  mv_pol<<<10240, 256, 0, stream>>>((const float4*)Wpol, (const float4*)x,
                                    (const float4*)vbuf, partP,
                                    ws + WS_DISC_POL);
  finish_pol<<<1, 1024, 0, stream>>>(partP, bpol, Whead, bhead, vbuf, pos,
                                     out);
}

// Round 17
// 110.463 us; speedup vs baseline: 4.5227x; 4.5227x over previous
//
#include <hip/hip_runtime.h>

#define HW 512
#define NSTATE (HW * HW)   // 262144
#define NC4_X 196608       // x as float4 (3*H*W/4)
#define NC4_POLROW 262144  // Wpol row stride in float4 (4 MiB)
#define NC4_V 65536        // v as float4

#define CH4 1024   // float4 per wave-chunk (16 KB)
#define NCH_X 192  // chunks per W1 row
#define SPAN_ROP 1024

// ws layout (float offsets)
#define WS_PART1 0      // 192*32 = 6144
#define WS_PARTP 6144   // 256*32 = 8192
#define WS_H2 14336     // 64
#define WS_P 14400      // 262144
#define WS_RD (WS_P + NSTATE)
#define WS_V (WS_RD + NSTATE)

#define SGB __builtin_amdgcn_sched_group_barrier

__device__ __forceinline__ float wred(float a) {
  a += __shfl_xor(a, 32);
  a += __shfl_xor(a, 16);
  a += __shfl_xor(a, 8);
  a += __shfl_xor(a, 4);
  a += __shfl_xor(a, 2);
  a += __shfl_xor(a, 1);
  return a;
}

__device__ __forceinline__ float span_dot(const float4* __restrict__ wp,
                                          const float4* __restrict__ xp) {
  float acc = 0.f;
#pragma unroll
  for (int bt = 0; bt < 2; ++bt) {
    float4 w[8], xv[8];
#pragma unroll
    for (int j = 0; j < 8; ++j) w[j] = wp[bt * 512 + j * 64];
#pragma unroll
    for (int j = 0; j < 8; ++j) xv[j] = xp[bt * 512 + j * 64];
    SGB(0x020, 16, 0);
#pragma unroll
    for (int j = 0; j < 8; ++j)
      acc += w[j].x * xv[j].x + w[j].y * xv[j].y + w[j].z * xv[j].z +
             w[j].w * xv[j].w;
  }
  return acc;
}

// ---------------------------------------------------------------------------
// K1: W1@x partials, flat-linear (~15 µs, at floor). 1536 blocks.
// ---------------------------------------------------------------------------
__global__ __launch_bounds__(256) void mv_w1(const float4* __restrict__ W1,
                                             const float4* __restrict__ x,
                                             float* __restrict__ part1) {
  int b = blockIdx.x;
  int row = b / 48, cb = b - row * 48;
  int tid = threadIdx.x, wave = tid >> 6, lane = tid & 63;
  int ch = cb * 4 + wave;
  const float4* __restrict__ wp =
      W1 + (size_t)row * NC4_X + (size_t)ch * CH4 + lane;
  const float4* __restrict__ xp = x + (size_t)ch * CH4 + lane;
  float acc = span_dot(wp, xp);
  acc = wred(acc);
  if (lane == 0) part1[ch * 32 + row] = acc;
}

// ---------------------------------------------------------------------------
// finish_h
// ---------------------------------------------------------------------------
__global__ __launch_bounds__(1024) void finish_h(
    const float* __restrict__ partials, const float* __restrict__ b1,
    const float* __restrict__ W2, const float* __restrict__ b2,
    float* __restrict__ h2out) {
  __shared__ float red[32][32];
  __shared__ float h1[32];
  int tid = threadIdx.x;
  int row = tid & 31, grp = tid >> 5;
  float s = 0.f;
  for (int b = grp; b < NCH_X; b += 32) s += partials[b * 32 + row];
  red[grp][row] = s;
  __syncthreads();
  if (tid < 32) {
    float t = b1[tid];
    for (int g = 0; g < 32; ++g) t += red[g][tid];
    h1[tid] = fmaxf(t, 0.f);
  }
  __syncthreads();
  if (tid < 64) {
    float t = b2[tid];
    for (int k = 0; k < 32; ++k) t += W2[tid * 32 + k] * h1[k];
    h2out[tid] = fmaxf(t, 0.f);
  }
}

// ---------------------------------------------------------------------------
// rop: R5 measured-fast form (warm ~19 µs, cold ~26). 1024 blocks.
// ---------------------------------------------------------------------------
__global__ __launch_bounds__(256) void rop_kernel(
    const float4* __restrict__ Wro4, const float* __restrict__ bro,
    const float4* __restrict__ Wri4, const float* __restrict__ bri,
    const float4* __restrict__ Wp4, const float* __restrict__ bp,
    const float* __restrict__ h2, float* __restrict__ p_out,
    float* __restrict__ rd_out) {
  __shared__ float dots[4][3][64];
  int tid = threadIdx.x;
  int wave = tid >> 6, lane = tid & 63;
  int grp = lane >> 4;
  float4 h4 = ((const float4*)h2)[lane & 15];
  int span = blockIdx.x * 4 + wave;
  size_t base = (size_t)span * SPAN_ROP;
  const float4* mats[3] = {Wro4, Wri4, Wp4};
#pragma unroll
  for (int m = 0; m < 3; ++m) {
    const float4* __restrict__ W = mats[m] + base + lane;
#pragma unroll
    for (int batch = 0; batch < 2; ++batch) {
      float4 w[8];
#pragma unroll
      for (int j = 0; j < 8; ++j) w[j] = W[(batch * 8 + j) * 64];
      SGB(0x020, 8, 0);
      float part[8];
#pragma unroll
      for (int j = 0; j < 8; ++j)
        part[j] = w[j].x * h4.x + w[j].y * h4.y + w[j].z * h4.z + w[j].w * h4.w;
#pragma unroll
      for (int j = 0; j < 8; ++j) {
        part[j] += __shfl_xor(part[j], 8);
        part[j] += __shfl_xor(part[j], 4);
        part[j] += __shfl_xor(part[j], 2);
        part[j] += __shfl_xor(part[j], 1);
      }
      if ((lane & 15) == 0) {
#pragma unroll
        for (int j = 0; j < 8; ++j)
          dots[wave][m][(batch * 8 + j) * 4 + grp] = part[j];
      }
    }
  }
  __syncthreads();
  int o = blockIdx.x * 256 + tid;
  float dro = dots[tid >> 6][0][tid & 63] + bro[o];
  float dri = dots[tid >> 6][1][tid & 63] + bri[o];
  float dp = dots[tid >> 6][2][tid & 63] + bp[o];
  float sro = 1.f / (1.f + __expf(-dro));
  float sri = 1.f / (1.f + __expf(-dri));
  float pv = 1.f / (1.f + __expf(-dp));
  p_out[o] = pv;
  rd_out[o] = sri - sro;
}

// ---------------------------------------------------------------------------
// K4: valiter REWRITE. R16 measured 18.3 µs, LDS-op bound (6.8e7 bank-
// conflict cycles, 13 scalar LDS ops/cell/iter). New form:
//  (1) u-space recurrence u' = max8(u)*p + rd  (init u=rd, 9 updates, final
//      max8) -> ONE barrier/iter, no vv array;
//  (2) p,rd live in registers (thread owns 4 fixed cells);
//  (3) all u traffic as aligned float4 (9 b128 reads + 1 write per 4 cells);
//  (4) active region shrinks 1 ring/pass ([q+1,35-q)) — stale cells outside
//      are provably never read (next pass reads region+1 ring exactly).
// u tile [38][44] (ring row 0/37, col 3/40 kept 0; cols 0-2,41-43 align pad),
// double-buffered. 384 threads (324 active), 1024 blocks, 4 blocks/CU.
// ---------------------------------------------------------------------------
#define VTILE 16
#define VHALO 10
#define ULW 44
#define ULH 38
__device__ __forceinline__ void row_win(const float* __restrict__ r,
                                        float e[6]) {
  float4 L = *reinterpret_cast<const float4*>(r - 4);
  float4 M = *reinterpret_cast<const float4*>(r);
  float4 R = *reinterpret_cast<const float4*>(r + 4);
  e[0] = L.w; e[1] = M.x; e[2] = M.y; e[3] = M.z; e[4] = M.w; e[5] = R.x;
}
__global__ __launch_bounds__(384) void valiter_kernel(
    const float* __restrict__ p, const float* __restrict__ rd,
    float* __restrict__ vout) {
  __shared__ float ua[ULH * ULW];
  __shared__ float ub[ULH * ULW];
  int tid = threadIdx.x;
  int blk = blockIdx.x;
  int ti = blk >> 5, tj = blk & 31;
  for (int idx = tid; idx < ULH * ULW; idx += 384) {
    ua[idx] = 0.f;
    ub[idx] = 0.f;
  }
  int i = tid / 9, j4 = tid - i * 9;  // interior row 0..35, f4-col 0..8
  bool active = (i < 36);
  int cb = 4 + 4 * j4;  // LDS col base of this thread's 4 cells
  float pp[4], rr[4];
  if (active) {
    int gi = ti * VTILE - VHALO + i;
    int gj0 = tj * VTILE - VHALO + 4 * j4;
#pragma unroll
    for (int k = 0; k < 4; ++k) {
      int gj = gj0 + k;
      bool ok = (gi >= 0) & (gi < HW) & (gj >= 0) & (gj < HW);
      int gidx = gi * HW + gj;
      pp[k] = ok ? p[gidx] : 0.f;
      rr[k] = ok ? rd[gidx] : 0.f;
    }
  }
  __syncthreads();  // zero-fill complete before interior init
  if (active) {
    *reinterpret_cast<float4*>(&ua[(i + 1) * ULW + cb]) =
        make_float4(rr[0], rr[1], rr[2], rr[3]);  // u_1 = rd
  }
  __syncthreads();
  float* src = ua;
  float* dst = ub;
  for (int q = 0; q < 9; ++q) {  // u_{q+2} = max8(u_{q+1})*p + rd
    int lo = q + 1, hi = 35 - q;
    if (active && i >= lo && i < hi && (4 * j4 + 4) > lo && (4 * j4) < hi) {
      float eA[6], eB[6], eC[6];
      row_win(src + i * ULW + cb, eA);
      row_win(src + (i + 1) * ULW + cb, eB);
      row_win(src + (i + 2) * ULW + cb, eC);
      float res[4];
#pragma unroll
      for (int k = 0; k < 4; ++k) {
        float a = fmaxf(fmaxf(eA[k], eA[k + 1]), eA[k + 2]);
        float c = fmaxf(fmaxf(eC[k], eC[k + 1]), eC[k + 2]);
        float b = fmaxf(eB[k], eB[k + 2]);  // center excluded
        float m = fmaxf(fmaxf(a, c), b);
        res[k] = m * pp[k] + rr[k];
      }
      *reinterpret_cast<float4*>(&dst[(i + 1) * ULW + cb]) =
          make_float4(res[0], res[1], res[2], res[3]);
    }
    __syncthreads();
    float* t_ = src;
    src = dst;
    dst = t_;
  }
  // final: v_10 = max8(u_10) on the 16x16 core
  if (active && i >= 10 && i < 26 && (4 * j4 + 4) > 10 && (4 * j4) < 26) {
    float eA[6], eB[6], eC[6];
    row_win(src + i * ULW + cb, eA);
    row_win(src + (i + 1) * ULW + cb, eB);
    row_win(src + (i + 2) * ULW + cb, eC);
#pragma unroll
    for (int k = 0; k < 4; ++k) {
      int cj = 4 * j4 + k;
      if (cj >= 10 && cj < 26) {
        float a = fmaxf(fmaxf(eA[k], eA[k + 1]), eA[k + 2]);
        float c = fmaxf(fmaxf(eC[k], eC[k + 1]), eC[k + 2]);
        float b = fmaxf(eB[k], eB[k + 2]);
        float m = fmaxf(fmaxf(a, c), b);
        vout[(ti * VTILE + i - 10) * HW + tj * VTILE + cj - 10] = m;
      }
    }
  }
}

// ---------------------------------------------------------------------------
// K5: all Wpol in one flat sweep (cold ~27 µs). 2048 blocks.
// ---------------------------------------------------------------------------
__global__ __launch_bounds__(256) void mv_pol(const float4* __restrict__ Wpol,
                                              const float4* __restrict__ x,
                                              const float4* __restrict__ v,
                                              float* __restrict__ partP) {
  int b = blockIdx.x;
  int tid = threadIdx.x, wave = tid >> 6, lane = tid & 63;
  int f = b * 4 + wave;
  int row = f >> 8, rc = f & 255;
  const float4* __restrict__ wp = Wpol + (size_t)f * CH4 + lane;
  const float4* __restrict__ xp =
      (rc < 64) ? (v + (size_t)rc * CH4 + lane)
                : (x + (size_t)(rc - 64) * CH4 + lane);
  float acc = span_dot(wp, xp);
  acc = wred(acc);
  if (lane == 0) partP[rc * 32 + row] = acc;
}

// ---------------------------------------------------------------------------
// finish_pol
// ---------------------------------------------------------------------------
__global__ __launch_bounds__(1024) void finish_pol(
    const float* __restrict__ partP, const float* __restrict__ bpol,
    const float* __restrict__ Whead, const float* __restrict__ bhead,
    const float* __restrict__ v, const int* __restrict__ pos,
    float* __restrict__ out) {
  __shared__ float red[32][32];
  __shared__ float hp[32];
  __shared__ float logits[8];
  int tid = threadIdx.x;
  int row = tid & 31, grp = tid >> 5;
  float s = 0.f;
  for (int b = grp; b < 256; b += 32) s += partP[b * 32 + row];
  red[grp][row] = s;
  __syncthreads();
  if (tid < 32) {
    float t = bpol[tid];
    for (int g = 0; g < 32; ++g) t += red[g][tid];
    hp[tid] = fmaxf(t, 0.f);
  }
  __syncthreads();
  if (tid < 8) {
    float t = bhead[tid];
    for (int k = 0; k < 32; ++k) t += Whead[tid * 32 + k] * hp[k];
    logits[tid] = t;
  }
  __syncthreads();
  if (tid == 0) {
    float mx = logits[0];
    for (int j = 1; j < 8; ++j) mx = fmaxf(mx, logits[j]);
    float e[8], sum = 0.f;
    for (int j = 0; j < 8; ++j) {
      e[j] = __expf(logits[j] - mx);
      sum += e[j];
    }
    for (int j = 0; j < 8; ++j) out[j] = e[j] / sum;
    out[8] = v[pos[0] * HW + pos[1]];
  }
}

extern "C" void kernel_launch(void* const* d_in, const int* in_sizes, int n_in,
                              void* d_out, int out_size, void* d_ws,
                              size_t ws_size, hipStream_t stream) {
  const float* x = (const float*)d_in[0];
  const int* pos = (const int*)d_in[1];
  const float* W1 = (const float*)d_in[2];
  const float* b1 = (const float*)d_in[3];
  const float* W2 = (const float*)d_in[4];
  const float* b2 = (const float*)d_in[5];
  const float* Wro = (const float*)d_in[6];
  const float* bro = (const float*)d_in[7];
  const float* Wri = (const float*)d_in[8];
  const float* bri = (const float*)d_in[9];
  const float* Wp = (const float*)d_in[10];
  const float* bp = (const float*)d_in[11];
  const float* Wpol = (const float*)d_in[12];
  const float* bpol = (const float*)d_in[13];
  const float* Whead = (const float*)d_in[14];
  const float* bhead = (const float*)d_in[15];
  float* ws = (float*)d_ws;
  float* out = (float*)d_out;

  float* part1 = ws + WS_PART1;
  float* partP = ws + WS_PARTP;
  float* h2 = ws + WS_H2;
  float* pbuf = ws + WS_P;
  float* rdbuf = ws + WS_RD;
  float* vbuf = ws + WS_V;

  mv_w1<<<1536, 256, 0, stream>>>((const float4*)W1, (const float4*)x, part1);
  finish_h<<<1, 1024, 0, stream>>>(part1, b1, W2, b2, h2);
  rop_kernel<<<1024, 256, 0, stream>>>((const float4*)Wro, bro,
                                       (const float4*)Wri, bri,
                                       (const float4*)Wp, bp, h2, pbuf, rdbuf);
  valiter_kernel<<<1024, 384, 0, stream>>>(pbuf, rdbuf, vbuf);
  mv_pol<<<2048, 256, 0, stream>>>((const float4*)Wpol, (const float4*)x,
                                   (const float4*)vbuf, partP);
  finish_pol<<<1, 1024, 0, stream>>>(partP, bpol, Whead, bhead, vbuf, pos,
                                     out);
}